// Round 1
// baseline (6165.076 us; speedup 1.0000x reference)
//
#include <hip/hip_runtime.h>

// Dilated conv2d: x[8,32,512,512] f32, w[64,32,5,9], dil=(2,3), pad=(2,4)
// -> out[8,64,508,496] f32.
// Block = (b, oh, 64-wide w tile). 256 threads: tid>>2 = cout (0..63),
// tid&3 = w-group of 16 outputs. Input slab for this output row staged in LDS
// once (32 cin x 5 taps x 88 w = 56KB), then register-blocked FMA loops.

#define CB 8
#define CIN 32
#define HH 512
#define WW 512
#define COUT 64
#define OH 508
#define OW 496
#define KH 5
#define KW 9
#define WTILE 64
#define SROW 88   // staged row width: 64 + (9-1)*3 = 88

__global__ __launch_bounds__(256, 2)
void conv_dil_f32(const float* __restrict__ x, const float* __restrict__ wgt,
                  float* __restrict__ out) {
    __shared__ float s_in[CIN * KH * SROW];  // 14080 floats = 56320 B

    const int wt = blockIdx.x;           // 0..7
    const int oh = blockIdx.y;           // 0..507
    const int b  = blockIdx.z;           // 0..7
    const int w0 = wt * WTILE;
    const int tid = threadIdx.x;

    // ---- stage input slab: rows ih = oh-2+2*r (r=0..4), iw = w0-4 .. w0+83 ----
    const int total = CIN * KH * SROW;   // 14080 = 55 * 256 exactly
    #pragma unroll 1
    for (int idx = tid; idx < total; idx += 256) {
        int cin = idx / (KH * SROW);
        int rem = idx - cin * (KH * SROW);
        int r   = rem / SROW;
        int wi  = rem - r * SROW;
        int ih  = oh - 2 + 2 * r;
        int iw  = w0 - 4 + wi;
        float v = 0.f;
        if ((unsigned)ih < (unsigned)HH && (unsigned)iw < (unsigned)WW)
            v = x[((b * CIN + cin) * HH + ih) * WW + iw];
        s_in[idx] = v;
    }
    __syncthreads();

    const int co    = tid >> 2;
    const int wg    = tid & 3;
    const int wbase = w0 + wg * 16;

    float acc[16];
    #pragma unroll
    for (int t = 0; t < 16; ++t) acc[t] = 0.f;

    const float* wp = wgt + co * (CIN * KH * KW);

    #pragma unroll 1
    for (int cin = 0; cin < CIN; ++cin) {
        #pragma unroll
        for (int r = 0; r < KH; ++r) {
            // 9 weights for this (co, cin, kh=r) row (4B-aligned -> scalar loads)
            const float* wr = wp + (cin * KH + r) * KW;
            float wk[9];
            #pragma unroll
            for (int k = 0; k < 9; ++k) wk[k] = wr[k];

            // 40 staged input floats for this row (10x ds_read_b128)
            const float* sp = &s_in[(cin * KH + r) * SROW + wg * 16];
            float xin[40];
            #pragma unroll
            for (int j = 0; j < 10; ++j) {
                float4 v = *(const float4*)(sp + 4 * j);
                xin[4*j+0] = v.x; xin[4*j+1] = v.y;
                xin[4*j+2] = v.z; xin[4*j+3] = v.w;
            }

            // 144 FMAs
            #pragma unroll
            for (int kw = 0; kw < KW; ++kw) {
                #pragma unroll
                for (int t = 0; t < 16; ++t)
                    acc[t] = fmaf(wk[kw], xin[3*kw + t], acc[t]);
            }
        }
    }

    // ---- store 16 outputs (4x float4). OW=496 is a multiple of 16, so each
    // 16-wide group is fully in-bounds or fully out. ----
    if (wbase < OW) {
        float* op = out + ((b * COUT + co) * OH + oh) * OW + wbase;
        #pragma unroll
        for (int j = 0; j < 4; ++j) {
            *(float4*)(op + 4*j) =
                make_float4(acc[4*j+0], acc[4*j+1], acc[4*j+2], acc[4*j+3]);
        }
    }
}

extern "C" void kernel_launch(void* const* d_in, const int* in_sizes, int n_in,
                              void* d_out, int out_size, void* d_ws, size_t ws_size,
                              hipStream_t stream) {
    const float* x = (const float*)d_in[0];
    const float* w = (const float*)d_in[1];
    float* out = (float*)d_out;

    dim3 grid(8 /*w tiles*/, OH, CB);
    dim3 block(256);
    conv_dil_f32<<<grid, block, 0, stream>>>(x, w, out);
}

// Round 2
// 943.009 us; speedup vs baseline: 6.5377x; 6.5377x over previous
//
#include <hip/hip_runtime.h>

// Dilated conv2d as 45-tap implicit GEMM with bf16 MFMA.
// x[8,32,512,512] f32, w[64,32,5,9], dil=(2,3), pad=(2,4) -> out[8,64,508,496] f32.
//
// Per tap (r,kw): out[co][pos] += sum_cin w[co][cin,r,kw] * x[cin][oh-2+2r][pos-4+3kw]
// = GEMM M=64(co) K=32(cin) N=pos, one mfma_f32_16x16x32_bf16 per 16x16 tile.
//
// LDS input slab: [r=5][wi=160][cin(pad 40)] bf16 = 64000 B -> B-frag = 1 ds_read_b128
// (lane l: wi = 3*kw + nbase + (l&15), cin = 8*(l>>4)..+7 contiguous).
// Weights repacked to d_ws as [tap][co][cin] bf16 -> A-frag = 1 coalesced dwordx4 (L2).

#define CB 8
#define CIN 32
#define HH 512
#define WW 512
#define COUT 64
#define OH 508
#define OW 496
#define KH 5
#define KW 9
#define NTAP 45
#define WTILE 128
#define SW 160   // staged width (>= 128 + 24 halo + 4 pad-left)
#define SP 40    // cin stride in LDS: 32 padded to 40 (80B: 16B-aligned, ~2-way banks)

typedef short short8 __attribute__((ext_vector_type(8)));
typedef float floatx4 __attribute__((ext_vector_type(4)));
typedef unsigned short u16;
typedef unsigned int u32;

__device__ __forceinline__ u16 f2bf(float f) {  // RNE f32->bf16
    u32 u = __float_as_uint(f);
    return (u16)((u + 0x7fffu + ((u >> 16) & 1u)) >> 16);
}

__global__ void repack_w_k(const float* __restrict__ w, u16* __restrict__ wr) {
    int idx = blockIdx.x * 256 + threadIdx.x;
    if (idx >= NTAP * COUT * CIN) return;
    int tap = idx / (COUT * CIN);
    int rem = idx - tap * (COUT * CIN);
    int co = rem / CIN;
    int ci = rem - co * CIN;
    int r  = tap / KW;
    int kw = tap - r * KW;
    wr[idx] = f2bf(w[((co * CIN + ci) * KH + r) * KW + kw]);
}

__global__ __launch_bounds__(256, 2)
void conv_mfma(const float* __restrict__ x, const u16* __restrict__ wrep,
               float* __restrict__ out) {
    __shared__ u16 s[KH * SW * SP];  // 64000 B -> 2 blocks/CU

    const int wt = blockIdx.x;
    const int oh = blockIdx.y;
    const int b  = blockIdx.z;
    const int w0 = wt * WTILE;
    const int tid = threadIdx.x;

    // ---- stage input slab with cin->innermost transpose ----
    // items (r, w4, cg): load 4 float4 (cin=4cg..+3, iw=4w4..+3), write 4x 8B.
    for (int it = tid; it < KH * (SW / 4) * (CIN / 4); it += 256) {
        int r   = it / ((SW / 4) * (CIN / 4));
        int rem = it - r * ((SW / 4) * (CIN / 4));
        int w4  = rem >> 3;
        int cg  = rem & 7;
        int ih  = oh - 2 + 2 * r;
        int iw0 = w0 - 4 + 4 * w4;
        float m[4][4];
        bool ok = ((unsigned)ih < HH) && ((unsigned)iw0 < WW);
        #pragma unroll
        for (int c = 0; c < 4; ++c) {
            float4 v;
            if (ok) v = *(const float4*)(x + ((size_t)((b * CIN + 4 * cg + c)) * HH + ih) * WW + iw0);
            else    v = make_float4(0.f, 0.f, 0.f, 0.f);
            m[c][0] = v.x; m[c][1] = v.y; m[c][2] = v.z; m[c][3] = v.w;
        }
        #pragma unroll
        for (int j = 0; j < 4; ++j) {
            u32 lo = (u32)f2bf(m[0][j]) | ((u32)f2bf(m[1][j]) << 16);
            u32 hi = (u32)f2bf(m[2][j]) | ((u32)f2bf(m[3][j]) << 16);
            u32* p = (u32*)&s[(size_t)(r * SW + 4 * w4 + j) * SP + 4 * cg];
            p[0] = lo;
            p[1] = hi;
        }
    }
    __syncthreads();

    const int lane = tid & 63;
    const int wave = tid >> 6;
    const int li   = lane & 15;
    const int h    = lane >> 4;
    const int posb = wave * 32;  // wave's local position base

    floatx4 acc[4][2];
    #pragma unroll
    for (int mi = 0; mi < 4; ++mi)
        #pragma unroll
        for (int ni = 0; ni < 2; ++ni)
            acc[mi][ni] = (floatx4){0.f, 0.f, 0.f, 0.f};

    // A-frag base: wrep[(tap*64 + mi*16 + li)*32 + 8h]
    const u16* abase = wrep + li * CIN + 8 * h;

    #pragma unroll 1
    for (int tap = 0; tap < NTAP; ++tap) {
        int r  = tap / KW;
        int kw = tap - r * KW;
        short8 a[4], bb[2];
        #pragma unroll
        for (int mi = 0; mi < 4; ++mi)
            a[mi] = *(const short8*)(abase + (tap * COUT + mi * 16) * CIN);
        const u16* bbase = s + (size_t)(r * SW + 3 * kw + posb + li) * SP + 8 * h;
        #pragma unroll
        for (int ni = 0; ni < 2; ++ni)
            bb[ni] = *(const short8*)(bbase + ni * 16 * SP);
        #pragma unroll
        for (int mi = 0; mi < 4; ++mi)
            #pragma unroll
            for (int ni = 0; ni < 2; ++ni)
                acc[mi][ni] = __builtin_amdgcn_mfma_f32_16x16x32_bf16(
                    a[mi], bb[ni], acc[mi][ni], 0, 0, 0);
    }

    // ---- epilogue: D frag row = (l>>4)*4 + reg -> co; col = l&15 -> pos ----
    #pragma unroll
    for (int ni = 0; ni < 2; ++ni) {
        int pos = w0 + posb + ni * 16 + li;
        if (pos < OW) {
            #pragma unroll
            for (int mi = 0; mi < 4; ++mi) {
                int co = mi * 16 + h * 4;
                float* op = out + (((size_t)(b * COUT + co) * OH + oh) * OW + pos);
                #pragma unroll
                for (int reg = 0; reg < 4; ++reg)
                    op[(size_t)reg * OH * OW] = acc[mi][ni][reg];
            }
        }
    }
}

extern "C" void kernel_launch(void* const* d_in, const int* in_sizes, int n_in,
                              void* d_out, int out_size, void* d_ws, size_t ws_size,
                              hipStream_t stream) {
    const float* x = (const float*)d_in[0];
    const float* w = (const float*)d_in[1];
    float* out = (float*)d_out;
    u16* wrep = (u16*)d_ws;  // 45*64*32*2 = 184320 B

    repack_w_k<<<(NTAP * COUT * CIN + 255) / 256, 256, 0, stream>>>(w, wrep);

    dim3 grid((OW + WTILE - 1) / WTILE, OH, CB);
    conv_mfma<<<grid, dim3(256), 0, stream>>>(x, wrep, out);
}

// Round 3
// 569.802 us; speedup vs baseline: 10.8197x; 1.6550x over previous
//
#include <hip/hip_runtime.h>

// Dilated conv2d as implicit GEMM, parity-ring edition.
// x[8,32,512,512] f32, w[64,32,5,9], dil=(2,3), pad=(2,4) -> out[8,64,508,496] f32.
//
// Block = (b, 128-wide pos tile, parity, chunk of 32 same-parity oh rows).
// Dilation 2 => same-parity oh rows share input rows; stepping oh by 4
// (2 rows/step, one per wo-wave-pair) needs only 2 NEW input rows per step.
// LDS = 8-slot ring of row-slabs (6 active + 2 prefetch), layout
// [oct=cin/8][wi=152][8 cin] bf16 with 16B oct pad: B-frag = 1 ds_read_b128,
// contiguous 256B per 16-lane group (conflict-free), no padding waste.
// Wave = 64co x 64pos (mi=4, ni=4): per tap 4 A-loads (global, L1-broadcast
// across the 4 waves) + 4 ds_read_b128 + 16 MFMA -> 256B L2 + 256B LDS per MFMA.
// Per step: issue 2-row prefetch loads -> 45 taps -> convert+ds_write -> barrier
// -> store (T14 async-stage split; one barrier per 720 block-MFMAs).

#define CIN 32
#define HH 512
#define WW 512
#define COUT 64
#define OH 508
#define OW 496
#define KH 5
#define KW 9

#define WTILE 128
#define SW 152              // staged width: 128 + 24 halo (origin iw = w0-4)
#define OCT_STRIDE 1224     // SW*8 + 8 elts = 2448B (16B-aligned, banks spread)
#define SLOT_STRIDE 4896    // 4 * OCT_STRIDE elts = 9792B per row-slab
#define NSLOT 8             // ring: 6 active + 2 prefetch (78336 B total)
#define NIT 304             // staging items per row: (SW/4)*8
#define STEPS 16            // 2 oh rows per step -> 32 same-parity oh per block

typedef short short8 __attribute__((ext_vector_type(8)));
typedef float floatx4 __attribute__((ext_vector_type(4)));
typedef unsigned short u16;
typedef unsigned int u32;

__device__ __forceinline__ u16 f2bf(float f) {  // RNE f32->bf16
    u32 u = __float_as_uint(f);
    return (u16)((u + 0x7fffu + ((u >> 16) & 1u)) >> 16);
}

__global__ void repack_w_k(const float* __restrict__ w, u16* __restrict__ wr) {
    int idx = blockIdx.x * 256 + threadIdx.x;
    if (idx >= KH * KW * COUT * CIN) return;
    int tap = idx / (COUT * CIN);
    int rem = idx - tap * (COUT * CIN);
    int co = rem / CIN;
    int ci = rem - co * CIN;
    int r  = tap / KW;
    int kw = tap - r * KW;
    wr[idx] = f2bf(w[((co * CIN + ci) * KH + r) * KW + kw]);
}

__global__ __launch_bounds__(256, 2)
void conv_ring(const float* __restrict__ x, const u16* __restrict__ wrep,
               float* __restrict__ out) {
    __shared__ u16 s[NSLOT * SLOT_STRIDE];  // 78336 B -> 2 blocks/CU

    const int bx     = blockIdx.x;          // 0..7: wt(2b) | parity(1b)
    const int wt     = bx & 3;
    const int parity = bx >> 2;
    const int chunk  = blockIdx.y;          // 0..7
    const int b      = blockIdx.z;          // 0..7
    const int w0     = wt * WTILE;
    const int oh0    = parity + 64 * chunk;
    const int ihbase = oh0 - 2;
    const int iwbase = w0 - 4;

    const int tid  = threadIdx.x;
    const int lane = tid & 63;
    const int wave = tid >> 6;
    const int wp   = wave & 1;   // pos half (64)
    const int wo   = wave >> 1;  // which of the 2 oh rows this step
    const int li   = lane & 15;
    const int h    = lane >> 4;

    const size_t cstr = (size_t)HH * WW;    // x channel stride
    const float* xb = x + (size_t)b * CIN * cstr;

    // ---------------- prologue: stage rows j = 0..5 ----------------
    for (int it = tid; it < 6 * NIT; it += 256) {
        int j   = it / NIT;
        int rem = it - j * NIT;
        int w4  = rem >> 3;
        int q   = rem & 7;      // cin quad: cin = 4q..4q+3
        int ih  = ihbase + 2 * j;
        int iw0 = iwbase + 4 * w4;
        float4 m0 = {0,0,0,0}, m1 = {0,0,0,0}, m2 = {0,0,0,0}, m3 = {0,0,0,0};
        if ((unsigned)ih < HH && (unsigned)iw0 < WW) {
            const float* p = xb + (size_t)(4 * q) * cstr + (size_t)ih * WW + iw0;
            m0 = *(const float4*)(p);
            m1 = *(const float4*)(p + cstr);
            m2 = *(const float4*)(p + 2 * cstr);
            m3 = *(const float4*)(p + 3 * cstr);
        }
        u16* dst = s + (j & 7) * SLOT_STRIDE + (q >> 1) * OCT_STRIDE + (q & 1) * 4;
        const float* f0 = (const float*)&m0; const float* f1 = (const float*)&m1;
        const float* f2 = (const float*)&m2; const float* f3 = (const float*)&m3;
        #pragma unroll
        for (int jj = 0; jj < 4; ++jj) {
            u32 lo = (u32)f2bf(f0[jj]) | ((u32)f2bf(f1[jj]) << 16);
            u32 hi = (u32)f2bf(f2[jj]) | ((u32)f2bf(f3[jj]) << 16);
            *(uint2*)(dst + (4 * w4 + jj) * 8) = make_uint2(lo, hi);
        }
    }
    __syncthreads();

    const u16* abase0 = wrep + li * CIN + 8 * h;
    const int  bfixed = h * OCT_STRIDE + (64 * wp + li) * 8;

    floatx4 acc[4][4];

    #pragma unroll 1
    for (int st = 0; st < STEPS; ++st) {
        #pragma unroll
        for (int mi = 0; mi < 4; ++mi)
            #pragma unroll
            for (int ni = 0; ni < 4; ++ni)
                acc[mi][ni] = (floatx4){0.f, 0.f, 0.f, 0.f};

        // ---- A. issue prefetch loads for rows 2st+6, 2st+7 (regs) ----
        const bool doPref = (st < STEPS - 1);
        float4 pv[3][4];
        #pragma unroll
        for (int k = 0; k < 3; ++k) {
            #pragma unroll
            for (int c = 0; c < 4; ++c) pv[k][c] = (float4){0,0,0,0};
            int it = tid + 256 * k;
            if (doPref && it < 2 * NIT) {
                int second = (it >= NIT);
                int rem = it - (second ? NIT : 0);
                int j   = 2 * st + 6 + second;
                int w4  = rem >> 3;
                int q   = rem & 7;
                int ih  = ihbase + 2 * j;
                int iw0 = iwbase + 4 * w4;
                if ((unsigned)ih < HH && (unsigned)iw0 < WW) {
                    const float* p = xb + (size_t)(4 * q) * cstr + (size_t)ih * WW + iw0;
                    pv[k][0] = *(const float4*)(p);
                    pv[k][1] = *(const float4*)(p + cstr);
                    pv[k][2] = *(const float4*)(p + 2 * cstr);
                    pv[k][3] = *(const float4*)(p + 3 * cstr);
                }
            }
        }

        // ---- B. 45 taps: 4 A-loads + 4 ds_read_b128 + 16 MFMA each ----
        const int js = 2 * st;
        #pragma unroll 1
        for (int r = 0; r < KH; ++r) {
            const u16* bb = s + ((js + wo + r) & 7) * SLOT_STRIDE + bfixed;
            const u16* ab = abase0 + (size_t)(r * KW) * (COUT * CIN);
            #pragma unroll 3
            for (int kw = 0; kw < KW; ++kw) {
                short8 af[4], bf_[4];
                #pragma unroll
                for (int mi = 0; mi < 4; ++mi)
                    af[mi] = *(const short8*)(ab + (kw * COUT + mi * 16) * CIN);
                #pragma unroll
                for (int ni = 0; ni < 4; ++ni)
                    bf_[ni] = *(const short8*)(bb + (16 * ni + 3 * kw) * 8);
                #pragma unroll
                for (int mi = 0; mi < 4; ++mi)
                    #pragma unroll
                    for (int ni = 0; ni < 4; ++ni)
                        acc[mi][ni] = __builtin_amdgcn_mfma_f32_16x16x32_bf16(
                            af[mi], bf_[ni], acc[mi][ni], 0, 0, 0);
            }
        }

        // ---- C. convert + ds_write the prefetched rows into ring ----
        if (doPref) {
            #pragma unroll
            for (int k = 0; k < 3; ++k) {
                int it = tid + 256 * k;
                if (it < 2 * NIT) {
                    int second = (it >= NIT);
                    int rem = it - (second ? NIT : 0);
                    int j   = 2 * st + 6 + second;
                    int w4  = rem >> 3;
                    int q   = rem & 7;
                    u16* dst = s + (j & 7) * SLOT_STRIDE + (q >> 1) * OCT_STRIDE + (q & 1) * 4;
                    const float* f0 = (const float*)&pv[k][0];
                    const float* f1 = (const float*)&pv[k][1];
                    const float* f2 = (const float*)&pv[k][2];
                    const float* f3 = (const float*)&pv[k][3];
                    #pragma unroll
                    for (int jj = 0; jj < 4; ++jj) {
                        u32 lo = (u32)f2bf(f0[jj]) | ((u32)f2bf(f1[jj]) << 16);
                        u32 hi = (u32)f2bf(f2[jj]) | ((u32)f2bf(f3[jj]) << 16);
                        *(uint2*)(dst + (4 * w4 + jj) * 8) = make_uint2(lo, hi);
                    }
                }
            }
        }
        __syncthreads();

        // ---- D. store this step's outputs ----
        const int oh = oh0 + 4 * st + 2 * wo;
        if (oh < OH) {
            #pragma unroll
            for (int ni = 0; ni < 4; ++ni) {
                const int posb = w0 + 64 * wp + 16 * ni;
                if (posb < OW) {
                    const int pos = posb + li;
                    #pragma unroll
                    for (int mi = 0; mi < 4; ++mi) {
                        float* op = out + (((size_t)(b * COUT + 16 * mi + 4 * h) * OH + oh) * OW) + pos;
                        #pragma unroll
                        for (int reg = 0; reg < 4; ++reg)
                            op[(size_t)reg * OH * OW] = acc[mi][ni][reg];
                    }
                }
            }
        }
    }
}

extern "C" void kernel_launch(void* const* d_in, const int* in_sizes, int n_in,
                              void* d_out, int out_size, void* d_ws, size_t ws_size,
                              hipStream_t stream) {
    const float* x = (const float*)d_in[0];
    const float* w = (const float*)d_in[1];
    float* out = (float*)d_out;
    u16* wrep = (u16*)d_ws;  // 45*64*32*2 = 184320 B

    repack_w_k<<<(KH * KW * COUT * CIN + 255) / 256, 256, 0, stream>>>(w, wrep);

    dim3 grid(8 /* wt(4) x parity(2) */, 8 /* chunks */, 8 /* batch */);
    conv_ring<<<grid, dim3(256), 0, stream>>>(x, wrep, out);
}